// Round 3
// baseline (3894.876 us; speedup 1.0000x reference)
//
#include <hip/hip_runtime.h>
#include <hip/hip_bf16.h>
#include <cstdint>

// Problem constants (match reference)
#define B_    8
#define CIN   3
#define NPTS  32768            // N
#define TOT   (B_*NPTS)        // 262144 nodes
#define COUT  128
#define KCH   4
#define NE    4194304          // edges
#define NF    12               // KCH*CIN features per node
#define NS    78               // upper-triangular entries of 12x12
#define BN_EPS 1e-5f

// ---------------- degree: deg[src] += w (self-loops removed) ----------------
__global__ __launch_bounds__(256) void k_deg(const int* __restrict__ src,
                                             const int* __restrict__ dst,
                                             const float* __restrict__ ew,
                                             float* __restrict__ deg) {
    int e = blockIdx.x * 256 + threadIdx.x;   // NE % 256 == 0
    int s = src[e], d = dst[e];
    float w = ew[e];
    if (s != d && w != 0.0f) atomicAdd(deg + s, w);
}

// ---------------- dis = deg>0 ? rsqrt(max(deg,1e-12)) : 0 (in place) --------
__global__ __launch_bounds__(256) void k_dis(float* __restrict__ deg) {
    int i = blockIdx.x * 256 + threadIdx.x;   // TOT % 256 == 0
    float v = deg[i];
    deg[i] = (v > 0.0f) ? rsqrtf(fmaxf(v, 1e-12f)) : 0.0f;
}

// ---------------- tx0: (B, CIN, N) fp32 -> (TOT, 3) fp32 --------------------
__global__ __launch_bounds__(256) void k_tx0(const float* __restrict__ x,
                                             float* __restrict__ tx0) {
    int i = blockIdx.x * 256 + threadIdx.x;
    int b = i >> 15;            // / NPTS
    int n = i & (NPTS - 1);
    const float* xb = x + (size_t)b * CIN * NPTS + n;
    tx0[i * 3 + 0] = xb[0];
    tx0[i * 3 + 1] = xb[NPTS];
    tx0[i * 3 + 2] = xb[2 * NPTS];
}

// ---------------- prop: tout[dst] += scale * norm_w * tin[src] --------------
__global__ __launch_bounds__(256) void k_prop(const int* __restrict__ src,
                                              const int* __restrict__ dst,
                                              const float* __restrict__ ew,
                                              const float* __restrict__ dis,
                                              const float* __restrict__ tin,
                                              float* __restrict__ tout,
                                              float scale) {
    int e = blockIdx.x * 256 + threadIdx.x;
    int s = src[e], d = dst[e];
    if (s == d) return;
    float w = ew[e];
    float nw = -dis[s] * w * dis[d] * scale;
    if (nw == 0.0f) return;
    const float* t = tin + (size_t)s * 3;
    float t0 = t[0], t1 = t[1], t2 = t[2];
    atomicAdd(tout + (size_t)d * 3 + 0, nw * t0);
    atomicAdd(tout + (size_t)d * 3 + 1, nw * t1);
    atomicAdd(tout + (size_t)d * 3 + 2, nw * t2);
}

// ---------------- tout -= tprev (finish T_k = 2*L*T_{k-1} - T_{k-2}) --------
__global__ __launch_bounds__(256) void k_sub(float* __restrict__ tout,
                                             const float* __restrict__ tprev) {
    int i = blockIdx.x * 256 + threadIdx.x;   // 3*TOT % 256 == 0
    tout[i] -= tprev[i];
}

// ---------------- moments: mom[0..11]=sum t, mom[12..89]=sum upper(t t^T) ---
__global__ __launch_bounds__(256) void k_moments(const float* __restrict__ tx0,
                                                 const float* __restrict__ tx1,
                                                 const float* __restrict__ tx2,
                                                 const float* __restrict__ tx3,
                                                 float* __restrict__ mom) {
    float m[NF];
    float s[NS];
#pragma unroll
    for (int a = 0; a < NF; ++a) m[a] = 0.0f;
#pragma unroll
    for (int a = 0; a < NS; ++a) s[a] = 0.0f;

    for (int i = blockIdx.x * blockDim.x + threadIdx.x; i < TOT;
         i += gridDim.x * blockDim.x) {
        float t[NF];
        t[0] = tx0[i * 3 + 0]; t[1]  = tx0[i * 3 + 1]; t[2]  = tx0[i * 3 + 2];
        t[3] = tx1[i * 3 + 0]; t[4]  = tx1[i * 3 + 1]; t[5]  = tx1[i * 3 + 2];
        t[6] = tx2[i * 3 + 0]; t[7]  = tx2[i * 3 + 1]; t[8]  = tx2[i * 3 + 2];
        t[9] = tx3[i * 3 + 0]; t[10] = tx3[i * 3 + 1]; t[11] = tx3[i * 3 + 2];
        int idx = 0;
#pragma unroll
        for (int a = 0; a < NF; ++a) {
            m[a] += t[a];
#pragma unroll
            for (int b = a; b < NF; ++b) s[idx++] += t[a] * t[b];
        }
    }
    // wave64 shuffle reduction
#pragma unroll
    for (int off = 32; off > 0; off >>= 1) {
#pragma unroll
        for (int a = 0; a < NF; ++a) m[a] += __shfl_down(m[a], off, 64);
#pragma unroll
        for (int a = 0; a < NS; ++a) s[a] += __shfl_down(s[a], off, 64);
    }
    if ((threadIdx.x & 63) == 0) {
#pragma unroll
        for (int a = 0; a < NF; ++a) atomicAdd(mom + a, m[a]);
#pragma unroll
        for (int a = 0; a < NS; ++a) atomicAdd(mom + NF + a, s[a]);
    }
}

// ---------------- fold BN + bias + gamma/beta into 12x128 weight + 128 bias -
__global__ __launch_bounds__(128) void k_prep(const float* __restrict__ mom,
                                              const float* __restrict__ weight,
                                              const float* __restrict__ bias,
                                              const float* __restrict__ gamma,
                                              const float* __restrict__ beta,
                                              float* __restrict__ wp,   // [12][128]
                                              float* __restrict__ bp) { // [128]
    int c = threadIdx.x;
    float w[NF];
#pragma unroll
    for (int f = 0; f < NF; ++f) w[f] = weight[f * COUT + c]; // (K*CIN, COUT) row-major

    const float inv = 1.0f / (float)TOT;
    float mu[NF];
#pragma unroll
    for (int a = 0; a < NF; ++a) mu[a] = mom[a] * inv;
    float mw = 0.0f;
#pragma unroll
    for (int a = 0; a < NF; ++a) mw += mu[a] * w[a];

    float q = 0.0f;
    int idx = NF;
#pragma unroll
    for (int a = 0; a < NF; ++a) {
#pragma unroll
        for (int b = a; b < NF; ++b) {
            float S2 = mom[idx++] * inv;
            q += ((a == b) ? 1.0f : 2.0f) * w[a] * w[b] * S2;
        }
    }
    float bc   = bias[c];
    float mean = mw + bc;
    float var  = q - mw * mw;          // bias term cancels in variance
    float sc   = gamma[c] * rsqrtf(var + BN_EPS);
    float sh   = (bc - mean) * sc + beta[c];
#pragma unroll
    for (int f = 0; f < NF; ++f) wp[f * COUT + c] = w[f] * sc;
    bp[c] = sh;
}

// ---------------- final: out[b][c][n] = relu(t . wp[:,c] + bp[c]) -----------
__global__ __launch_bounds__(256) void k_out(const float* __restrict__ tx0,
                                             const float* __restrict__ tx1,
                                             const float* __restrict__ tx2,
                                             const float* __restrict__ tx3,
                                             const float* __restrict__ wp,
                                             const float* __restrict__ bp,
                                             float* __restrict__ out) {
    __shared__ float sw[NF * COUT];
    __shared__ float sb[COUT];
    for (int j = threadIdx.x; j < NF * COUT; j += 256) sw[j] = wp[j];
    if (threadIdx.x < COUT) sb[threadIdx.x] = bp[threadIdx.x];
    __syncthreads();

    int i = blockIdx.x * 256 + threadIdx.x;
    int b = i >> 15;
    int n = i & (NPTS - 1);

    float t[NF];
    t[0] = tx0[i * 3 + 0]; t[1]  = tx0[i * 3 + 1]; t[2]  = tx0[i * 3 + 2];
    t[3] = tx1[i * 3 + 0]; t[4]  = tx1[i * 3 + 1]; t[5]  = tx1[i * 3 + 2];
    t[6] = tx2[i * 3 + 0]; t[7]  = tx2[i * 3 + 1]; t[8]  = tx2[i * 3 + 2];
    t[9] = tx3[i * 3 + 0]; t[10] = tx3[i * 3 + 1]; t[11] = tx3[i * 3 + 2];

    float* o = out + (size_t)b * COUT * NPTS + n;
#pragma unroll 4
    for (int c = 0; c < COUT; ++c) {
        float acc = sb[c];
#pragma unroll
        for (int f = 0; f < NF; ++f) acc += t[f] * sw[f * COUT + c];
        o[(size_t)c * NPTS] = fmaxf(acc, 0.0f);
    }
}

extern "C" void kernel_launch(void* const* d_in, const int* in_sizes, int n_in,
                              void* d_out, int out_size, void* d_ws, size_t ws_size,
                              hipStream_t stream) {
    const float* x      = (const float*)d_in[0];
    const int*   ei     = (const int*)d_in[1];
    const float* ew     = (const float*)d_in[2];
    const float* weight = (const float*)d_in[3];
    const float* bias   = (const float*)d_in[4];
    const float* gamma  = (const float*)d_in[5];
    const float* beta   = (const float*)d_in[6];
    float* out = (float*)d_out;

    const int* src = ei;
    const int* dst = ei + NE;

    // workspace layout (floats)
    float* ws   = (float*)d_ws;
    float* deg  = ws;                       // TOT      (becomes dis in place)
    float* tx1  = ws + (size_t)TOT;         // 3*TOT
    float* tx2  = ws + (size_t)4 * TOT;     // 3*TOT
    float* tx3  = ws + (size_t)7 * TOT;     // 3*TOT
    float* mom  = ws + (size_t)10 * TOT;    // 128 (90 used)
    float* wp   = mom + 128;                // 12*128
    float* bp   = wp + NF * COUT;           // 128
    float* tx0  = bp + COUT;                // 3*TOT

    // zero all scatter-accumulation targets: deg, tx1..tx3, mom (contiguous)
    hipMemsetAsync(ws, 0, ((size_t)10 * TOT + 128) * sizeof(float), stream);

    dim3 blk(256);
    dim3 gE(NE / 256);       // 16384
    dim3 gT(TOT / 256);      // 1024
    dim3 g3T(3 * TOT / 256); // 3072

    k_deg<<<gE, blk, 0, stream>>>(src, dst, ew, deg);
    k_dis<<<gT, blk, 0, stream>>>(deg);
    k_tx0<<<gT, blk, 0, stream>>>(x, tx0);

    // T1 = L_hat T0
    k_prop<<<gE, blk, 0, stream>>>(src, dst, ew, deg, tx0, tx1, 1.0f);
    // T2 = 2 L_hat T1 - T0
    k_prop<<<gE, blk, 0, stream>>>(src, dst, ew, deg, tx1, tx2, 2.0f);
    k_sub<<<g3T, blk, 0, stream>>>(tx2, tx0);
    // T3 = 2 L_hat T2 - T1
    k_prop<<<gE, blk, 0, stream>>>(src, dst, ew, deg, tx2, tx3, 2.0f);
    k_sub<<<g3T, blk, 0, stream>>>(tx3, tx1);

    // BN statistics via 12-dim moment matrix
    k_moments<<<dim3(1024), blk, 0, stream>>>(tx0, tx1, tx2, tx3, mom);
    k_prep<<<dim3(1), dim3(128), 0, stream>>>(mom, weight, bias, gamma, beta, wp, bp);

    // fused linear + BN + ReLU + transpose, fp32 store
    k_out<<<gT, blk, 0, stream>>>(tx0, tx1, tx2, tx3, wp, bp, out);
}

// Round 4
// 1018.465 us; speedup vs baseline: 3.8243x; 3.8243x over previous
//
#include <hip/hip_runtime.h>
#include <cstdint>

// Problem constants (match reference)
#define B_    8
#define CIN   3
#define NPTS  32768            // N
#define TOT   (B_*NPTS)        // 262144 nodes
#define COUT  128
#define NE    4194304          // edges
#define NF    12               // K*CIN features per node
#define NMOM  90               // 12 first moments + 78 upper-tri second moments
#define MSTRIDE 17             // spread mom accumulators across cachelines
#define BN_EPS 1e-5f

// ===================== shared small kernels =====================

// (B, CIN, N) fp32 -> (TOT, 3) packed fp32
__global__ __launch_bounds__(256) void k_tx0(const float* __restrict__ x,
                                             float* __restrict__ tx0) {
    int i = blockIdx.x * 256 + threadIdx.x;
    int b = i >> 15;
    int n = i & (NPTS - 1);
    const float* xb = x + (size_t)b * CIN * NPTS + n;
    tx0[i * 3 + 0] = xb[0];
    tx0[i * 3 + 1] = xb[NPTS];
    tx0[i * 3 + 2] = xb[2 * NPTS];
}

// decode moment output index o in [0,90):
//  o<12  -> (o, 12)  (first moment, multiplied with constant-1 column 12)
//  o>=12 -> upper-triangular pair (a,b), row-major a=0..11, b=a..11
__device__ __forceinline__ void decode_pair(int o, int& A, int& Bb) {
    if (o < 12) { A = o; Bb = 12; return; }
    int p = o - 12, base = 0; A = 0; Bb = 0;
#pragma unroll
    for (int aa = 0; aa < 12; ++aa) {
        int len = 12 - aa;
        bool in = (p >= base) && (p < base + len);
        if (in) { A = aa; Bb = aa + (p - base); }
        base += len;
    }
}

// LDS-tiled moment reduction: mom[o*MSTRIDE] += sum over nodes of t[a]*t[b]
// grid = 256 blocks x 256 threads; each block does 4 tiles of 256 nodes.
__global__ __launch_bounds__(256) void k_moments(const float* __restrict__ tx0,
                                                 const float* __restrict__ tx1,
                                                 const float* __restrict__ tx2,
                                                 const float* __restrict__ tx3,
                                                 float* __restrict__ mom) {
    __shared__ float L[256 * 13];
    __shared__ float R[4][96];
    const int tid = threadIdx.x, lane = tid & 63, w = tid >> 6;

    int a1, b1, a2 = 12, b2 = 12;
    decode_pair(lane, a1, b1);
    if (lane < 26) decode_pair(64 + lane, a2, b2);

    float acc1 = 0.0f, acc2 = 0.0f;

    const int TPB = (TOT / 256) / 256;  // 4 tiles per block
    for (int t = 0; t < TPB; ++t) {
        int tile = blockIdx.x * TPB + t;
        int node = tile * 256 + tid;
        __syncthreads();               // protect L from previous tile's readers
        float* Ld = &L[tid * 13];
        Ld[0] = tx0[node * 3 + 0]; Ld[1]  = tx0[node * 3 + 1]; Ld[2]  = tx0[node * 3 + 2];
        Ld[3] = tx1[node * 3 + 0]; Ld[4]  = tx1[node * 3 + 1]; Ld[5]  = tx1[node * 3 + 2];
        Ld[6] = tx2[node * 3 + 0]; Ld[7]  = tx2[node * 3 + 1]; Ld[8]  = tx2[node * 3 + 2];
        Ld[9] = tx3[node * 3 + 0]; Ld[10] = tx3[node * 3 + 1]; Ld[11] = tx3[node * 3 + 2];
        Ld[12] = 1.0f;
        __syncthreads();
        // wave w reduces nodes [w*64, w*64+64) of this tile; lane owns outputs lane, 64+lane
        const int nb = w * 64;
#pragma unroll 4
        for (int i = 0; i < 64; ++i) {
            const float* Ln = &L[(nb + i) * 13];
            acc1 += Ln[a1] * Ln[b1];
            if (lane < 26) acc2 += Ln[a2] * Ln[b2];
        }
    }
    R[w][lane] = acc1;
    if (lane < 26) R[w][64 + lane] = acc2;
    __syncthreads();
    if (tid < NMOM) {
        float s = R[0][tid] + R[1][tid] + R[2][tid] + R[3][tid];
        atomicAdd(mom + tid * MSTRIDE, s);
    }
}

// fold BN + bias + gamma/beta into 12x128 weight + 128 bias
__global__ __launch_bounds__(128) void k_prep(const float* __restrict__ mom,
                                              const float* __restrict__ weight,
                                              const float* __restrict__ bias,
                                              const float* __restrict__ gamma,
                                              const float* __restrict__ beta,
                                              float* __restrict__ wp,
                                              float* __restrict__ bp) {
    int c = threadIdx.x;
    float w[NF];
#pragma unroll
    for (int f = 0; f < NF; ++f) w[f] = weight[f * COUT + c];

    const float inv = 1.0f / (float)TOT;
    float mu[NF];
#pragma unroll
    for (int a = 0; a < NF; ++a) mu[a] = mom[a * MSTRIDE] * inv;
    float mw = 0.0f;
#pragma unroll
    for (int a = 0; a < NF; ++a) mw += mu[a] * w[a];

    float q = 0.0f;
    int idx = NF;
#pragma unroll
    for (int a = 0; a < NF; ++a) {
#pragma unroll
        for (int b = a; b < NF; ++b) {
            float S2 = mom[idx++ * MSTRIDE] * inv;
            q += ((a == b) ? 1.0f : 2.0f) * w[a] * w[b] * S2;
        }
    }
    float bc   = bias[c];
    float mean = mw + bc;
    float var  = q - mw * mw;
    float sc   = gamma[c] * rsqrtf(var + BN_EPS);
    float sh   = (bc - mean) * sc + beta[c];
#pragma unroll
    for (int f = 0; f < NF; ++f) wp[f * COUT + c] = w[f] * sc;
    bp[c] = sh;
}

// fused linear + BN + ReLU + transpose, fp32 store
__global__ __launch_bounds__(256) void k_out(const float* __restrict__ tx0,
                                             const float* __restrict__ tx1,
                                             const float* __restrict__ tx2,
                                             const float* __restrict__ tx3,
                                             const float* __restrict__ wp,
                                             const float* __restrict__ bp,
                                             float* __restrict__ out) {
    __shared__ float sw[NF * COUT];
    __shared__ float sb[COUT];
    for (int j = threadIdx.x; j < NF * COUT; j += 256) sw[j] = wp[j];
    if (threadIdx.x < COUT) sb[threadIdx.x] = bp[threadIdx.x];
    __syncthreads();

    int i = blockIdx.x * 256 + threadIdx.x;
    int b = i >> 15;
    int n = i & (NPTS - 1);

    float t[NF];
    t[0] = tx0[i * 3 + 0]; t[1]  = tx0[i * 3 + 1]; t[2]  = tx0[i * 3 + 2];
    t[3] = tx1[i * 3 + 0]; t[4]  = tx1[i * 3 + 1]; t[5]  = tx1[i * 3 + 2];
    t[6] = tx2[i * 3 + 0]; t[7]  = tx2[i * 3 + 1]; t[8]  = tx2[i * 3 + 2];
    t[9] = tx3[i * 3 + 0]; t[10] = tx3[i * 3 + 1]; t[11] = tx3[i * 3 + 2];

    float* o = out + (size_t)b * COUT * NPTS + n;
#pragma unroll 4
    for (int c = 0; c < COUT; ++c) {
        float acc = sb[c];
#pragma unroll
        for (int f = 0; f < NF; ++f) acc += t[f] * sw[f * COUT + c];
        o[(size_t)c * NPTS] = fmaxf(acc, 0.0f);
    }
}

// ===================== CSR (gather) path =====================

// fused degree accumulation + dst histogram
__global__ __launch_bounds__(256) void k_hist(const int* __restrict__ src,
                                              const int* __restrict__ dst,
                                              const float* __restrict__ ew,
                                              float* __restrict__ deg,
                                              int* __restrict__ cnt) {
    int e = blockIdx.x * 256 + threadIdx.x;
    int s = src[e], d = dst[e];
    float w = ew[e];
    if (s != d && w != 0.0f) {
        atomicAdd(deg + s, w);
        atomicAdd(cnt + d, 1);
    }
}

// block sums of cnt (for scan) + dis = rsqrt(deg) in place
__global__ __launch_bounds__(256) void k_bsum_dis(const int* __restrict__ cnt,
                                                  int* __restrict__ bsum,
                                                  float* __restrict__ deg) {
    int i = blockIdx.x * 256 + threadIdx.x;
    float v = deg[i];
    deg[i] = (v > 0.0f) ? rsqrtf(fmaxf(v, 1e-12f)) : 0.0f;

    int c = cnt[i];
#pragma unroll
    for (int off = 32; off > 0; off >>= 1) c += __shfl_down(c, off, 64);
    __shared__ int wsm[4];
    int lane = threadIdx.x & 63, w = threadIdx.x >> 6;
    if (lane == 0) wsm[w] = c;
    __syncthreads();
    if (threadIdx.x == 0) bsum[blockIdx.x] = wsm[0] + wsm[1] + wsm[2] + wsm[3];
}

// exclusive scan of bsum[1024] in place (single block, 256 threads x 4 elems)
__global__ __launch_bounds__(256) void k_scan_bsum(int* __restrict__ bsum) {
    int tid = threadIdx.x, lane = tid & 63, w = tid >> 6;
    int v0 = bsum[tid*4], v1 = bsum[tid*4+1], v2 = bsum[tid*4+2], v3 = bsum[tid*4+3];
    int s1 = v0 + v1, s2 = s1 + v2, T = s2 + v3;
    int inc = T;
#pragma unroll
    for (int d = 1; d < 64; d <<= 1) {
        int u = __shfl_up(inc, d, 64);
        if (lane >= d) inc += u;
    }
    __shared__ int wt[4];
    if (lane == 63) wt[w] = inc;
    __syncthreads();
    int wpre = 0;
#pragma unroll
    for (int k = 0; k < 4; ++k) if (k < w) wpre += wt[k];
    int excl = wpre + inc - T;
    bsum[tid*4+0] = excl;
    bsum[tid*4+1] = excl + v0;
    bsum[tid*4+2] = excl + s1;
    bsum[tid*4+3] = excl + s2;
}

// block exclusive scan of cnt + global block offset -> off; also pos = off (aliased in place)
__global__ __launch_bounds__(256) void k_scan(const int* __restrict__ bsum,
                                              int* __restrict__ cntpos,
                                              int* __restrict__ off) {
    int i = blockIdx.x * 256 + threadIdx.x;
    int tid = threadIdx.x, lane = tid & 63, w = tid >> 6;
    int v = cntpos[i];
    int inc = v;
#pragma unroll
    for (int d = 1; d < 64; d <<= 1) {
        int u = __shfl_up(inc, d, 64);
        if (lane >= d) inc += u;
    }
    __shared__ int wt[4];
    if (lane == 63) wt[w] = inc;
    __syncthreads();
    int wpre = 0;
#pragma unroll
    for (int k = 0; k < 4; ++k) if (k < w) wpre += wt[k];
    int excl = bsum[blockIdx.x] + wpre + inc - v;
    off[i] = excl;
    cntpos[i] = excl;                       // pos init
    if (i == TOT - 1) off[TOT] = excl + v;  // total valid edges
}

// scatter edges into CSR slots with precomputed normalized weight
__global__ __launch_bounds__(256) void k_fill(const int* __restrict__ src,
                                              const int* __restrict__ dst,
                                              const float* __restrict__ ew,
                                              const float* __restrict__ dis,
                                              int* __restrict__ pos,
                                              int* __restrict__ csr_s,
                                              float* __restrict__ csr_w) {
    int e = blockIdx.x * 256 + threadIdx.x;
    int s = src[e], d = dst[e];
    float w = ew[e];
    if (s != d && w != 0.0f) {
        float nw = -dis[s] * w * dis[d];
        int p = atomicAdd(pos + d, 1);
        csr_s[p] = s;
        csr_w[p] = nw;
    }
}

// gather prop: tout[n] = scale * sum_j nw_j * tin[src_j]  (- tprev[n] if given)
__global__ __launch_bounds__(256) void k_prop_g(const int* __restrict__ off,
                                                const int* __restrict__ csr_s,
                                                const float* __restrict__ csr_w,
                                                const float* __restrict__ tin,
                                                const float* __restrict__ tprev,
                                                float* __restrict__ tout,
                                                float scale) {
    int n = blockIdx.x * 256 + threadIdx.x;
    int b0 = off[n], b1 = off[n + 1];
    float a0 = 0.f, a1 = 0.f, a2 = 0.f;
    for (int j = b0; j < b1; ++j) {
        int s = csr_s[j];
        float nw = csr_w[j];
        const float* t = tin + (size_t)s * 3;
        a0 += nw * t[0]; a1 += nw * t[1]; a2 += nw * t[2];
    }
    float r0 = scale * a0, r1 = scale * a1, r2 = scale * a2;
    if (tprev) {
        r0 -= tprev[n * 3 + 0]; r1 -= tprev[n * 3 + 1]; r2 -= tprev[n * 3 + 2];
    }
    tout[n * 3 + 0] = r0; tout[n * 3 + 1] = r1; tout[n * 3 + 2] = r2;
}

// ===================== fallback (scatter) path =====================

__global__ __launch_bounds__(256) void k_deg(const int* __restrict__ src,
                                             const int* __restrict__ dst,
                                             const float* __restrict__ ew,
                                             float* __restrict__ deg) {
    int e = blockIdx.x * 256 + threadIdx.x;
    int s = src[e], d = dst[e];
    float w = ew[e];
    if (s != d && w != 0.0f) atomicAdd(deg + s, w);
}

__global__ __launch_bounds__(256) void k_dis(float* __restrict__ deg) {
    int i = blockIdx.x * 256 + threadIdx.x;
    float v = deg[i];
    deg[i] = (v > 0.0f) ? rsqrtf(fmaxf(v, 1e-12f)) : 0.0f;
}

__global__ __launch_bounds__(256) void k_prop(const int* __restrict__ src,
                                              const int* __restrict__ dst,
                                              const float* __restrict__ ew,
                                              const float* __restrict__ dis,
                                              const float* __restrict__ tin,
                                              float* __restrict__ tout,
                                              float scale) {
    int e = blockIdx.x * 256 + threadIdx.x;
    int s = src[e], d = dst[e];
    if (s == d) return;
    float w = ew[e];
    float nw = -dis[s] * w * dis[d] * scale;
    if (nw == 0.0f) return;
    const float* t = tin + (size_t)s * 3;
    atomicAdd(tout + (size_t)d * 3 + 0, nw * t[0]);
    atomicAdd(tout + (size_t)d * 3 + 1, nw * t[1]);
    atomicAdd(tout + (size_t)d * 3 + 2, nw * t[2]);
}

__global__ __launch_bounds__(256) void k_sub(float* __restrict__ tout,
                                             const float* __restrict__ tprev) {
    int i = blockIdx.x * 256 + threadIdx.x;
    tout[i] -= tprev[i];
}

// ===================== launcher =====================

extern "C" void kernel_launch(void* const* d_in, const int* in_sizes, int n_in,
                              void* d_out, int out_size, void* d_ws, size_t ws_size,
                              hipStream_t stream) {
    const float* x      = (const float*)d_in[0];
    const int*   ei     = (const int*)d_in[1];
    const float* ew     = (const float*)d_in[2];
    const float* weight = (const float*)d_in[3];
    const float* bias   = (const float*)d_in[4];
    const float* gamma  = (const float*)d_in[5];
    const float* beta   = (const float*)d_in[6];
    float* out = (float*)d_out;

    const int* src = ei;
    const int* dst = ei + NE;

    dim3 blk(256);
    dim3 gE(NE / 256);       // 16384
    dim3 gT(TOT / 256);      // 1024
    dim3 g3T(3 * TOT / 256); // 3072
    dim3 gM(256);            // moments

    const size_t csr_need = ((size_t)15 * TOT + 4288 + 2 * (size_t)NE) * 4;

    if (ws_size >= csr_need) {
        // ---------- CSR gather path ----------
        float* ws    = (float*)d_ws;
        float* deg   = ws;                                    // TOT
        int*   cnt   = (int*)(ws + TOT);                      // TOT (becomes pos)
        float* mom   = ws + (size_t)2 * TOT;                  // 1536
        int*   off   = (int*)(ws + (size_t)2 * TOT + 1536);   // TOT+64
        int*   bsum  = off + TOT + 64;                        // 1024
        float* wp    = (float*)(bsum + 1024);                 // 1536
        float* bp    = wp + 1536;                             // 128
        float* tx0   = bp + 128;                              // 3*TOT
        float* tx1   = tx0 + (size_t)3 * TOT;
        float* tx2   = tx1 + (size_t)3 * TOT;
        float* tx3   = tx2 + (size_t)3 * TOT;
        int*   csr_s = (int*)(tx3 + (size_t)3 * TOT);         // NE
        float* csr_w = (float*)(csr_s + NE);                  // NE

        // zero deg + cnt + mom (contiguous)
        hipMemsetAsync(ws, 0, ((size_t)2 * TOT + 1536) * sizeof(float), stream);

        k_hist<<<gE, blk, 0, stream>>>(src, dst, ew, deg, cnt);
        k_bsum_dis<<<gT, blk, 0, stream>>>(cnt, bsum, deg);
        k_scan_bsum<<<dim3(1), blk, 0, stream>>>(bsum);
        k_scan<<<gT, blk, 0, stream>>>(bsum, cnt, off);
        k_tx0<<<gT, blk, 0, stream>>>(x, tx0);
        k_fill<<<gE, blk, 0, stream>>>(src, dst, ew, deg, cnt, csr_s, csr_w);

        k_prop_g<<<gT, blk, 0, stream>>>(off, csr_s, csr_w, tx0, nullptr, tx1, 1.0f);
        k_prop_g<<<gT, blk, 0, stream>>>(off, csr_s, csr_w, tx1, tx0, tx2, 2.0f);
        k_prop_g<<<gT, blk, 0, stream>>>(off, csr_s, csr_w, tx2, tx1, tx3, 2.0f);

        k_moments<<<gM, blk, 0, stream>>>(tx0, tx1, tx2, tx3, mom);
        k_prep<<<dim3(1), dim3(128), 0, stream>>>(mom, weight, bias, gamma, beta, wp, bp);
        k_out<<<gT, blk, 0, stream>>>(tx0, tx1, tx2, tx3, wp, bp, out);
    } else {
        // ---------- fallback scatter path ----------
        float* ws  = (float*)d_ws;
        float* deg = ws;                        // TOT (becomes dis)
        float* tx1 = ws + (size_t)TOT;          // 3*TOT
        float* tx2 = ws + (size_t)4 * TOT;      // 3*TOT
        float* tx3 = ws + (size_t)7 * TOT;      // 3*TOT
        float* mom = ws + (size_t)10 * TOT;     // 1536
        float* wp  = mom + 1536;                // 1536
        float* bp  = wp + 1536;                 // 128
        float* tx0 = bp + 128;                  // 3*TOT

        hipMemsetAsync(ws, 0, ((size_t)10 * TOT + 1536) * sizeof(float), stream);

        k_deg<<<gE, blk, 0, stream>>>(src, dst, ew, deg);
        k_dis<<<gT, blk, 0, stream>>>(deg);
        k_tx0<<<gT, blk, 0, stream>>>(x, tx0);

        k_prop<<<gE, blk, 0, stream>>>(src, dst, ew, deg, tx0, tx1, 1.0f);
        k_prop<<<gE, blk, 0, stream>>>(src, dst, ew, deg, tx1, tx2, 2.0f);
        k_sub<<<g3T, blk, 0, stream>>>(tx2, tx0);
        k_prop<<<gE, blk, 0, stream>>>(src, dst, ew, deg, tx2, tx3, 2.0f);
        k_sub<<<g3T, blk, 0, stream>>>(tx3, tx1);

        k_moments<<<gM, blk, 0, stream>>>(tx0, tx1, tx2, tx3, mom);
        k_prep<<<dim3(1), dim3(128), 0, stream>>>(mom, weight, bias, gamma, beta, wp, bp);
        k_out<<<gT, blk, 0, stream>>>(tx0, tx1, tx2, tx3, wp, bp, out);
    }
}

// Round 5
// 392.310 us; speedup vs baseline: 9.9281x; 2.5961x over previous
//
#include <hip/hip_runtime.h>
#include <cstdint>

// Problem constants (match reference)
#define B_    8
#define CIN   3
#define NPTS  32768            // N
#define TOT   (B_*NPTS)        // 262144 nodes
#define COUT  128
#define NE    4194304          // edges
#define NF    12               // K*CIN features per node
#define NMOM  90
#define MSTRIDE 17
#define BN_EPS 1e-5f

#define NBKT  256              // buckets
#define BKSZ  1024             // nodes per bucket (TOT/NBKT)
#define TILE  4096             // edges per scatter block
#define EPT   16               // edges per thread (TILE/256)

// ===================== sorted-CSR build =====================

// global histograms of valid edges by src-bucket and dst-bucket
__global__ __launch_bounds__(256) void k_count(const int* __restrict__ src,
                                               const int* __restrict__ dst,
                                               const float* __restrict__ ew,
                                               int* __restrict__ g_hs,
                                               int* __restrict__ g_hd) {
    __shared__ int hs[NBKT], hd[NBKT];
    int t = threadIdx.x;
    if (t < NBKT) { hs[t] = 0; hd[t] = 0; }
    __syncthreads();
    int base = blockIdx.x * 16384 + t;      // 256 blocks x 64 edges/thread
    for (int k = 0; k < 64; ++k) {
        int e = base + k * 256;
        int s = src[e], d = dst[e];
        float w = ew[e];
        if (s != d && w != 0.0f) {
            atomicAdd(&hs[s >> 10], 1);
            atomicAdd(&hd[d >> 10], 1);
        }
    }
    __syncthreads();
    if (t < NBKT) {
        if (hs[t]) atomicAdd(g_hs + t, hs[t]);
        if (hd[t]) atomicAdd(g_hd + t, hd[t]);
    }
}

// exclusive scan of both 256-bin histograms; init region cursors
__global__ __launch_bounds__(256) void k_scan2(const int* __restrict__ g_hs,
                                               const int* __restrict__ g_hd,
                                               int* __restrict__ off_s,
                                               int* __restrict__ off_d,
                                               int* __restrict__ gp_s,
                                               int* __restrict__ gp_d) {
    int t = threadIdx.x, lane = t & 63, w = t >> 6;
    __shared__ int wt[2][4];
    int v1 = g_hs[t], v2 = g_hd[t];
    int i1 = v1, i2 = v2;
#pragma unroll
    for (int d = 1; d < 64; d <<= 1) {
        int u1 = __shfl_up(i1, d, 64), u2 = __shfl_up(i2, d, 64);
        if (lane >= d) { i1 += u1; i2 += u2; }
    }
    if (lane == 63) { wt[0][w] = i1; wt[1][w] = i2; }
    __syncthreads();
    int p1 = 0, p2 = 0;
#pragma unroll
    for (int k = 0; k < 4; ++k) if (k < w) { p1 += wt[0][k]; p2 += wt[1][k]; }
    int e1 = p1 + i1 - v1, e2 = p2 + i2 - v2;
    off_s[t] = e1; gp_s[t] = e1;
    off_d[t] = e2; gp_d[t] = e2;
    if (t == 255) { off_s[256] = e1 + v1; off_d[256] = e2 + v2; }
}

// tile-local counting sort -> chunked coalesced flush into bucket regions
// mode 0: bin by src, record {s&1023, w}   (for deg)
// mode 1: bin by dst, record {s | (d&1023)<<18, w}  (for props)
__global__ __launch_bounds__(256) void k_scatter(const int* __restrict__ src,
                                                 const int* __restrict__ dst,
                                                 const float* __restrict__ ew,
                                                 int* __restrict__ gpos,
                                                 int2* __restrict__ binned,
                                                 int mode) {
    __shared__ int lhist[NBKT], lbase[NBKT], cnt2[NBKT], gbase[NBKT];
    __shared__ int2 sorted[TILE];
    __shared__ unsigned char sbk[TILE];
    __shared__ int wt[4];
    int t = threadIdx.x;
    if (t < NBKT) { lhist[t] = 0; cnt2[t] = 0; }
    __syncthreads();

    int es[EPT], ed[EPT]; float ef[EPT];
    int base = blockIdx.x * TILE + t;
#pragma unroll
    for (int k = 0; k < EPT; ++k) {
        int e = base + k * 256;
        es[k] = src[e]; ed[k] = dst[e]; ef[k] = ew[e];
    }
#pragma unroll
    for (int k = 0; k < EPT; ++k) {
        if (es[k] != ed[k] && ef[k] != 0.0f) {
            int b = (mode ? ed[k] : es[k]) >> 10;
            atomicAdd(&lhist[b], 1);
        }
    }
    __syncthreads();
    // block-local exclusive scan of lhist + claim global region chunk
    {
        int lane = t & 63, wv = t >> 6;
        int v = (t < NBKT) ? lhist[t] : 0;
        int inc = v;
#pragma unroll
        for (int d = 1; d < 64; d <<= 1) {
            int u = __shfl_up(inc, d, 64);
            if (lane >= d) inc += u;
        }
        if (t < NBKT && lane == 63) wt[wv] = inc;
        __syncthreads();
        if (t < NBKT) {
            int pre = 0;
#pragma unroll
            for (int k2 = 0; k2 < 4; ++k2) if (k2 < wv) pre += wt[k2];
            int excl = pre + inc - v;
            lbase[t] = excl;
            gbase[t] = atomicAdd(gpos + t, v);
        }
    }
    __syncthreads();
#pragma unroll
    for (int k = 0; k < EPT; ++k) {
        if (es[k] != ed[k] && ef[k] != 0.0f) {
            int b, w0;
            if (mode) { b = ed[k] >> 10; w0 = es[k] | ((ed[k] & 1023) << 18); }
            else      { b = es[k] >> 10; w0 = es[k] & 1023; }
            int p = atomicAdd(&cnt2[b], 1);
            int idx = lbase[b] + p;
            sorted[idx] = make_int2(w0, __float_as_int(ef[k]));
            sbk[idx] = (unsigned char)b;
        }
    }
    __syncthreads();
    int tot = lbase[NBKT - 1] + lhist[NBKT - 1];
    for (int i = t; i < tot; i += 256) {
        int b = sbk[i];
        binned[(size_t)gbase[b] + (i - lbase[b])] = sorted[i];
    }
}

// per-bucket deg reduce (LDS float atomics) -> dis = rsqrt
__global__ __launch_bounds__(512) void k_degdis(const int* __restrict__ off_s,
                                                const int2* __restrict__ binned,
                                                float* __restrict__ dis) {
    __shared__ float acc[BKSZ];
    int t = threadIdx.x, b = blockIdx.x;
    acc[t] = 0.f; acc[t + 512] = 0.f;
    __syncthreads();
    int b0 = off_s[b], b1 = off_s[b + 1];
    for (int i = b0 + t; i < b1; i += 512) {
        int2 r = binned[i];
        atomicAdd(&acc[r.x], __int_as_float(r.y));
    }
    __syncthreads();
#pragma unroll
    for (int j = 0; j < 2; ++j) {
        int i = t + j * 512;
        float v = acc[i];
        dis[b * BKSZ + i] = (v > 0.f) ? rsqrtf(fmaxf(v, 1e-12f)) : 0.f;
    }
}

// block-per-bucket gather prop via LDS accumulator:
// tout[n] = -dis[n]*scale * sum_j w_j*dis[s_j]*tin[s_j]  - tprev[n]
__global__ __launch_bounds__(512) void k_prop(const int* __restrict__ off_d,
                                              const int2* __restrict__ binned,
                                              const float* __restrict__ dis,
                                              const float* __restrict__ tin,
                                              const float* __restrict__ tprev,
                                              float* __restrict__ tout,
                                              float scale) {
    __shared__ float acc[BKSZ * 3];
    int t = threadIdx.x, b = blockIdx.x;
    for (int i = t; i < BKSZ * 3; i += 512) acc[i] = 0.f;
    __syncthreads();
    int b0 = off_d[b], b1 = off_d[b + 1];
    for (int i = b0 + t; i < b1; i += 512) {
        int2 r = binned[i];
        int s  = r.x & 0x3FFFF;
        int dl = ((unsigned)r.x) >> 18;
        float nw = __int_as_float(r.y) * dis[s];
        const float* ts = tin + (size_t)s * 3;
        atomicAdd(&acc[dl * 3 + 0], nw * ts[0]);
        atomicAdd(&acc[dl * 3 + 1], nw * ts[1]);
        atomicAdd(&acc[dl * 3 + 2], nw * ts[2]);
    }
    __syncthreads();
#pragma unroll
    for (int j = 0; j < 2; ++j) {
        int i = t + j * 512;
        int n = b * BKSZ + i;
        float dn = -dis[n] * scale;
        float r0 = dn * acc[i * 3 + 0];
        float r1 = dn * acc[i * 3 + 1];
        float r2 = dn * acc[i * 3 + 2];
        if (tprev) {
            r0 -= tprev[n * 3 + 0]; r1 -= tprev[n * 3 + 1]; r2 -= tprev[n * 3 + 2];
        }
        tout[n * 3 + 0] = r0; tout[n * 3 + 1] = r1; tout[n * 3 + 2] = r2;
    }
}

// ===================== shared small kernels =====================

__global__ __launch_bounds__(256) void k_tx0(const float* __restrict__ x,
                                             float* __restrict__ tx0) {
    int i = blockIdx.x * 256 + threadIdx.x;
    int b = i >> 15;
    int n = i & (NPTS - 1);
    const float* xb = x + (size_t)b * CIN * NPTS + n;
    tx0[i * 3 + 0] = xb[0];
    tx0[i * 3 + 1] = xb[NPTS];
    tx0[i * 3 + 2] = xb[2 * NPTS];
}

__device__ __forceinline__ void decode_pair(int o, int& A, int& Bb) {
    if (o < 12) { A = o; Bb = 12; return; }
    int p = o - 12, base = 0; A = 0; Bb = 0;
#pragma unroll
    for (int aa = 0; aa < 12; ++aa) {
        int len = 12 - aa;
        bool in = (p >= base) && (p < base + len);
        if (in) { A = aa; Bb = aa + (p - base); }
        base += len;
    }
}

__global__ __launch_bounds__(256) void k_moments(const float* __restrict__ tx0,
                                                 const float* __restrict__ tx1,
                                                 const float* __restrict__ tx2,
                                                 const float* __restrict__ tx3,
                                                 float* __restrict__ mom) {
    __shared__ float L[256 * 13];
    __shared__ float R[4][96];
    const int tid = threadIdx.x, lane = tid & 63, w = tid >> 6;

    int a1, b1, a2 = 12, b2 = 12;
    decode_pair(lane, a1, b1);
    if (lane < 26) decode_pair(64 + lane, a2, b2);

    float acc1 = 0.0f, acc2 = 0.0f;
    const int TPB = (TOT / 256) / 256;
    for (int t = 0; t < TPB; ++t) {
        int node = (blockIdx.x * TPB + t) * 256 + tid;
        __syncthreads();
        float* Ld = &L[tid * 13];
        Ld[0] = tx0[node * 3 + 0]; Ld[1]  = tx0[node * 3 + 1]; Ld[2]  = tx0[node * 3 + 2];
        Ld[3] = tx1[node * 3 + 0]; Ld[4]  = tx1[node * 3 + 1]; Ld[5]  = tx1[node * 3 + 2];
        Ld[6] = tx2[node * 3 + 0]; Ld[7]  = tx2[node * 3 + 1]; Ld[8]  = tx2[node * 3 + 2];
        Ld[9] = tx3[node * 3 + 0]; Ld[10] = tx3[node * 3 + 1]; Ld[11] = tx3[node * 3 + 2];
        Ld[12] = 1.0f;
        __syncthreads();
        const int nb = w * 64;
#pragma unroll 4
        for (int i = 0; i < 64; ++i) {
            const float* Ln = &L[(nb + i) * 13];
            acc1 += Ln[a1] * Ln[b1];
            if (lane < 26) acc2 += Ln[a2] * Ln[b2];
        }
    }
    R[w][lane] = acc1;
    if (lane < 26) R[w][64 + lane] = acc2;
    __syncthreads();
    if (tid < NMOM) {
        float s = R[0][tid] + R[1][tid] + R[2][tid] + R[3][tid];
        atomicAdd(mom + tid * MSTRIDE, s);
    }
}

__global__ __launch_bounds__(128) void k_prep(const float* __restrict__ mom,
                                              const float* __restrict__ weight,
                                              const float* __restrict__ bias,
                                              const float* __restrict__ gamma,
                                              const float* __restrict__ beta,
                                              float* __restrict__ wp,
                                              float* __restrict__ bp) {
    int c = threadIdx.x;
    float w[NF];
#pragma unroll
    for (int f = 0; f < NF; ++f) w[f] = weight[f * COUT + c];

    const float inv = 1.0f / (float)TOT;
    float mu[NF];
#pragma unroll
    for (int a = 0; a < NF; ++a) mu[a] = mom[a * MSTRIDE] * inv;
    float mw = 0.0f;
#pragma unroll
    for (int a = 0; a < NF; ++a) mw += mu[a] * w[a];

    float q = 0.0f;
    int idx = NF;
#pragma unroll
    for (int a = 0; a < NF; ++a) {
#pragma unroll
        for (int b = a; b < NF; ++b) {
            float S2 = mom[idx++ * MSTRIDE] * inv;
            q += ((a == b) ? 1.0f : 2.0f) * w[a] * w[b] * S2;
        }
    }
    float bc   = bias[c];
    float mean = mw + bc;
    float var  = q - mw * mw;
    float sc   = gamma[c] * rsqrtf(var + BN_EPS);
    float sh   = (bc - mean) * sc + beta[c];
#pragma unroll
    for (int f = 0; f < NF; ++f) wp[f * COUT + c] = w[f] * sc;
    bp[c] = sh;
}

__global__ __launch_bounds__(256) void k_out(const float* __restrict__ tx0,
                                             const float* __restrict__ tx1,
                                             const float* __restrict__ tx2,
                                             const float* __restrict__ tx3,
                                             const float* __restrict__ wp,
                                             const float* __restrict__ bp,
                                             float* __restrict__ out) {
    __shared__ float sw[NF * COUT];
    __shared__ float sb[COUT];
    for (int j = threadIdx.x; j < NF * COUT; j += 256) sw[j] = wp[j];
    if (threadIdx.x < COUT) sb[threadIdx.x] = bp[threadIdx.x];
    __syncthreads();

    int i = blockIdx.x * 256 + threadIdx.x;
    int b = i >> 15;
    int n = i & (NPTS - 1);

    float t[NF];
    t[0] = tx0[i * 3 + 0]; t[1]  = tx0[i * 3 + 1]; t[2]  = tx0[i * 3 + 2];
    t[3] = tx1[i * 3 + 0]; t[4]  = tx1[i * 3 + 1]; t[5]  = tx1[i * 3 + 2];
    t[6] = tx2[i * 3 + 0]; t[7]  = tx2[i * 3 + 1]; t[8]  = tx2[i * 3 + 2];
    t[9] = tx3[i * 3 + 0]; t[10] = tx3[i * 3 + 1]; t[11] = tx3[i * 3 + 2];

    float* o = out + (size_t)b * COUT * NPTS + n;
#pragma unroll 4
    for (int c = 0; c < COUT; ++c) {
        float acc = sb[c];
#pragma unroll
        for (int f = 0; f < NF; ++f) acc += t[f] * sw[f * COUT + c];
        o[(size_t)c * NPTS] = fmaxf(acc, 0.0f);
    }
}

// ===================== fallback (scatter-atomic) path =====================

__global__ __launch_bounds__(256) void k_deg_fb(const int* src, const int* dst,
                                                const float* ew, float* deg) {
    int e = blockIdx.x * 256 + threadIdx.x;
    int s = src[e], d = dst[e];
    float w = ew[e];
    if (s != d && w != 0.0f) atomicAdd(deg + s, w);
}
__global__ __launch_bounds__(256) void k_dis_fb(float* deg) {
    int i = blockIdx.x * 256 + threadIdx.x;
    float v = deg[i];
    deg[i] = (v > 0.0f) ? rsqrtf(fmaxf(v, 1e-12f)) : 0.0f;
}
__global__ __launch_bounds__(256) void k_prop_fb(const int* src, const int* dst,
                                                 const float* ew, const float* dis,
                                                 const float* tin, float* tout, float scale) {
    int e = blockIdx.x * 256 + threadIdx.x;
    int s = src[e], d = dst[e];
    if (s == d) return;
    float w = ew[e];
    float nw = -dis[s] * w * dis[d] * scale;
    if (nw == 0.0f) return;
    const float* t = tin + (size_t)s * 3;
    atomicAdd(tout + (size_t)d * 3 + 0, nw * t[0]);
    atomicAdd(tout + (size_t)d * 3 + 1, nw * t[1]);
    atomicAdd(tout + (size_t)d * 3 + 2, nw * t[2]);
}
__global__ __launch_bounds__(256) void k_sub_fb(float* tout, const float* tprev) {
    int i = blockIdx.x * 256 + threadIdx.x;
    tout[i] -= tprev[i];
}

// ===================== launcher =====================

extern "C" void kernel_launch(void* const* d_in, const int* in_sizes, int n_in,
                              void* d_out, int out_size, void* d_ws, size_t ws_size,
                              hipStream_t stream) {
    const float* x      = (const float*)d_in[0];
    const int*   ei     = (const int*)d_in[1];
    const float* ew     = (const float*)d_in[2];
    const float* weight = (const float*)d_in[3];
    const float* bias   = (const float*)d_in[4];
    const float* gamma  = (const float*)d_in[5];
    const float* beta   = (const float*)d_in[6];
    float* out = (float*)d_out;

    const int* src = ei;
    const int* dst = ei + NE;

    dim3 blk(256);
    dim3 gT(TOT / 256);      // 1024

    // new-path workspace (4B units):
    // binned[2*NE] | dis[TOT] | tx0..tx3[12*TOT] | hist_s[256] hist_d[256] mom[1536]
    // | off_s[257] off_d[257] gp_s[256] gp_d[256] | wp[1536] bp[128]
    const size_t need = ((size_t)2 * NE + (size_t)13 * TOT + 2048 + 1026 + 512 + 1664) * 4;

    if (ws_size >= need) {
        int*   wsI    = (int*)d_ws;
        int2*  binned = (int2*)wsI;
        float* dis    = (float*)(wsI + (size_t)2 * NE);
        float* tx0    = dis + TOT;
        float* tx1    = tx0 + (size_t)3 * TOT;
        float* tx2    = tx1 + (size_t)3 * TOT;
        float* tx3    = tx2 + (size_t)3 * TOT;
        int*   hist_s = (int*)(tx3 + (size_t)3 * TOT);   // 256
        int*   hist_d = hist_s + 256;                    // 256
        float* mom    = (float*)(hist_d + 256);          // 1536
        int*   off_s  = (int*)(mom + 1536);              // 257
        int*   off_d  = off_s + 257;                     // 257
        int*   gp_s   = off_d + 257;                     // 256
        int*   gp_d   = gp_s + 256;                      // 256
        float* wp     = (float*)(gp_d + 256);            // 1536
        float* bp     = wp + 1536;                       // 128

        // zero hist_s, hist_d, mom (contiguous 2048 ints)
        hipMemsetAsync(hist_s, 0, 2048 * sizeof(int), stream);

        k_count  <<<dim3(256),  blk, 0, stream>>>(src, dst, ew, hist_s, hist_d);
        k_scan2  <<<dim3(1),    blk, 0, stream>>>(hist_s, hist_d, off_s, off_d, gp_s, gp_d);
        k_scatter<<<dim3(1024), blk, 0, stream>>>(src, dst, ew, gp_s, binned, 0); // by src
        k_degdis <<<dim3(256),  dim3(512), 0, stream>>>(off_s, binned, dis);
        k_tx0    <<<gT,         blk, 0, stream>>>(x, tx0);
        k_scatter<<<dim3(1024), blk, 0, stream>>>(src, dst, ew, gp_d, binned, 1); // by dst (reuse buffer)

        k_prop<<<dim3(256), dim3(512), 0, stream>>>(off_d, binned, dis, tx0, nullptr, tx1, 1.0f);
        k_prop<<<dim3(256), dim3(512), 0, stream>>>(off_d, binned, dis, tx1, tx0,     tx2, 2.0f);
        k_prop<<<dim3(256), dim3(512), 0, stream>>>(off_d, binned, dis, tx2, tx1,     tx3, 2.0f);

        k_moments<<<dim3(256), blk, 0, stream>>>(tx0, tx1, tx2, tx3, mom);
        k_prep   <<<dim3(1), dim3(128), 0, stream>>>(mom, weight, bias, gamma, beta, wp, bp);
        k_out    <<<gT, blk, 0, stream>>>(tx0, tx1, tx2, tx3, wp, bp, out);
    } else {
        // fallback scatter-atomic path (known-correct)
        dim3 gE(NE / 256);
        dim3 g3T(3 * TOT / 256);
        float* ws  = (float*)d_ws;
        float* deg = ws;
        float* tx1 = ws + (size_t)TOT;
        float* tx2 = ws + (size_t)4 * TOT;
        float* tx3 = ws + (size_t)7 * TOT;
        float* mom = ws + (size_t)10 * TOT;
        float* wp  = mom + 1536;
        float* bp  = wp + 1536;
        float* tx0 = bp + 128;

        hipMemsetAsync(ws, 0, ((size_t)10 * TOT + 1536) * sizeof(float), stream);

        k_deg_fb<<<gE, blk, 0, stream>>>(src, dst, ew, deg);
        k_dis_fb<<<gT, blk, 0, stream>>>(deg);
        k_tx0   <<<gT, blk, 0, stream>>>(x, tx0);

        k_prop_fb<<<gE, blk, 0, stream>>>(src, dst, ew, deg, tx0, tx1, 1.0f);
        k_prop_fb<<<gE, blk, 0, stream>>>(src, dst, ew, deg, tx1, tx2, 2.0f);
        k_sub_fb <<<g3T, blk, 0, stream>>>(tx2, tx0);
        k_prop_fb<<<gE, blk, 0, stream>>>(src, dst, ew, deg, tx2, tx3, 2.0f);
        k_sub_fb <<<g3T, blk, 0, stream>>>(tx3, tx1);

        k_moments<<<dim3(256), blk, 0, stream>>>(tx0, tx1, tx2, tx3, mom);
        k_prep   <<<dim3(1), dim3(128), 0, stream>>>(mom, weight, bias, gamma, beta, wp, bp);
        k_out    <<<gT, blk, 0, stream>>>(tx0, tx1, tx2, tx3, wp, bp, out);
    }
}